// Round 10
// baseline (331.675 us; speedup 1.0000x reference)
//
#include <hip/hip_runtime.h>
#include <hip/hip_bf16.h>
#include <math.h>

typedef short bf16x8 __attribute__((ext_vector_type(8)));
typedef float f32x4 __attribute__((ext_vector_type(4)));

#define MFMA_B16(A, B, C) __builtin_amdgcn_mfma_f32_16x16x32_bf16(A, B, C, 0, 0, 0)

#define NBATCH 8
#define CIN 256
#define NPIX 4096

__device__ __forceinline__ unsigned short f2b(float f) {
    union { float f; unsigned int u; } v;
    v.f = f;
    return (unsigned short)((v.u + 0x7fffu + ((v.u >> 16) & 1u)) >> 16);
}

// ---------------------------------------------------------------------------
// Kernel A: 1x1-conv QKV projection.
//   qT,kT: [B][N][32] bf16 (d=16..31 zero pad)   v: [B][256][N] bf16
// Block: 256 thr (4 waves), one (batch, 64-pixel tile). Wave w owns out-chans
// [64w,64w+64); waves 0/1 additionally compute q/k; waves 2/3 write the pads.
// ---------------------------------------------------------------------------
__global__ __launch_bounds__(256, 2) void qkv_kernel(
    const float* __restrict__ x,
    const float* __restrict__ Wq, const float* __restrict__ bq,
    const float* __restrict__ Wk, const float* __restrict__ bk,
    const float* __restrict__ Wv, const float* __restrict__ bv,
    unsigned short* __restrict__ qT, unsigned short* __restrict__ kT,
    unsigned short* __restrict__ vv)
{
    constexpr int XSTR = 264;                       // 16B-aligned row stride, breaks pow2 banks
    __shared__ __align__(16) unsigned short xs[64 * XSTR];  // x tile, [n][c] bf16
    const int b     = blockIdx.x >> 6;
    const int nbase = (blockIdx.x & 63) * 64;
    const int tid = threadIdx.x;
    const int w  = tid >> 6;
    const int l  = tid & 63;
    const int g  = l >> 4;
    const int ln = l & 15;

    // stage x[b][:, nbase..nbase+63] -> xs[n][c] (bf16, transposed)
    {
        const float* xp = x + (size_t)b * CIN * NPIX + nbase + l;   // coalesced over lanes
        unsigned short* xsp = xs + l * XSTR + w * 64;
        #pragma unroll
        for (int cc = 0; cc < 32; ++cc) {
            float v0 = xp[(size_t)(w * 64 + 2 * cc)     * NPIX];
            float v1 = xp[(size_t)(w * 64 + 2 * cc + 1) * NPIX];
            unsigned int pk = (unsigned int)f2b(v0) | ((unsigned int)f2b(v1) << 16);
            *(unsigned int*)(xsp + 2 * cc) = pk;
        }
    }
    __syncthreads();

    const f32x4 vzero = {0.f, 0.f, 0.f, 0.f};
    f32x4 acc[4][4];   // [ct][nt] : v out-chans
    f32x4 accq[4];     // [nt]     : q (wave0) / k (wave1)
    #pragma unroll
    for (int i = 0; i < 4; ++i) {
        accq[i] = vzero;
        #pragma unroll
        for (int j = 0; j < 4; ++j) acc[i][j] = vzero;
    }

    for (int ks = 0; ks < 8; ++ks) {
        const int k0 = ks * 32;
        bf16x8 xf[4];
        #pragma unroll
        for (int nt = 0; nt < 4; ++nt)
            xf[nt] = *(const bf16x8*)(xs + (nt * 16 + ln) * XSTR + k0 + g * 8);
        #pragma unroll
        for (int ct = 0; ct < 4; ++ct) {
            const float* wp = Wv + (size_t)(w * 64 + ct * 16 + ln) * CIN + k0 + g * 8;
            bf16x8 wf;
            #pragma unroll
            for (int j = 0; j < 8; ++j) wf[j] = (short)f2b(wp[j]);
            #pragma unroll
            for (int nt = 0; nt < 4; ++nt)
                acc[ct][nt] = MFMA_B16(wf, xf[nt], acc[ct][nt]);
        }
        if (w < 2) {
            const float* wqk = (w == 0 ? Wq : Wk) + (size_t)ln * CIN + k0 + g * 8;
            bf16x8 wf;
            #pragma unroll
            for (int j = 0; j < 8; ++j) wf[j] = (short)f2b(wqk[j]);
            #pragma unroll
            for (int nt = 0; nt < 4; ++nt)
                accq[nt] = MFMA_B16(wf, xf[nt], accq[nt]);
        }
    }

    // v epilogue: D row = 4g+r (out-chan), col = ln (pixel)
    #pragma unroll
    for (int ct = 0; ct < 4; ++ct) {
        #pragma unroll
        for (int r = 0; r < 4; ++r) {
            const int c = w * 64 + ct * 16 + g * 4 + r;
            const float bias = bv[c];
            #pragma unroll
            for (int nt = 0; nt < 4; ++nt)
                vv[((size_t)b * CIN + c) * NPIX + nbase + nt * 16 + ln] =
                    f2b(acc[ct][nt][r] + bias);
        }
    }
    if (w < 2) {
        unsigned short* oq = (w == 0 ? qT : kT);
        const float* bias  = (w == 0 ? bq : bk);
        #pragma unroll
        for (int r = 0; r < 4; ++r) {
            const int d = g * 4 + r;
            const float bi = bias[d];
            #pragma unroll
            for (int nt = 0; nt < 4; ++nt)
                oq[((size_t)b * NPIX + nbase + nt * 16 + ln) * 32 + d] =
                    f2b(accq[nt][r] + bi);
        }
    } else {
        // zero the d=16..31 pad rows (ws is re-poisoned 0xAA every launch!)
        unsigned short* oq = (w == 2 ? qT : kT);
        unsigned short* p  = oq + ((size_t)b * NPIX + nbase + l) * 32 + 16;
        uint4 z; z.x = 0; z.y = 0; z.z = 0; z.w = 0;
        *(uint4*)p       = z;
        *(uint4*)(p + 8) = z;
    }
}

// ---------------------------------------------------------------------------
// Kernel B: flash attention + residual.
// Block: 256 thr (4 waves), one (batch, 64-query tile). Wave w owns channels
// [64w,64w+64). Swapped QK^T (A=keys) makes softmax reduction lane-local-ish:
// 2x shfl_xor + one small LDS exchange across waves. P staged in LDS bf16.
// Exactly 2 barriers per 64-key tile.
// ---------------------------------------------------------------------------
__global__ __launch_bounds__(256, 2) void attn_kernel(
    const float* __restrict__ x, const float* __restrict__ gamma_p,
    const unsigned short* __restrict__ qT, const unsigned short* __restrict__ kT,
    const unsigned short* __restrict__ vv, float* __restrict__ out)
{
    constexpr int PSTR = 72;   // 144B row stride: ~2-way bank aliasing (free)
    __shared__ __align__(16) unsigned short P_lds[64 * PSTR];
    __shared__ __align__(16) float smax[64 * 4];
    __shared__ __align__(16) float ssum[64 * 4];
    const int b     = blockIdx.x & 7;            // XCD-affine: batch -> XCD
    const int qbase = (blockIdx.x >> 3) * 64;
    const int tid = threadIdx.x;
    const int w  = tid >> 6;
    const int l  = tid & 63;
    const int g  = l >> 4;
    const int ln = l & 15;
    const float gamma = *gamma_p;

    bf16x8 qf[4];
    #pragma unroll
    for (int qt = 0; qt < 4; ++qt)
        qf[qt] = *(const bf16x8*)(qT + ((size_t)b * NPIX + qbase + qt * 16 + ln) * 32 + g * 8);

    const f32x4 vzero = {0.f, 0.f, 0.f, 0.f};
    f32x4 acc[4][4];   // [qt][ct]
    #pragma unroll
    for (int i = 0; i < 4; ++i) {
        #pragma unroll
        for (int j = 0; j < 4; ++j) acc[i][j] = vzero;
    }
    float m_run[4] = {-INFINITY, -INFINITY, -INFINITY, -INFINITY};
    float l_run[4] = {0.f, 0.f, 0.f, 0.f};

    for (int kt = 0; kt < 64; ++kt) {
        const int k0 = kt * 64;
        // this wave's 16-key slice, S^T = K·Q : lane holds S[n=qt*16+ln][m=w*16+4g+r]
        const bf16x8 kf = *(const bf16x8*)(kT + ((size_t)b * NPIX + k0 + w * 16 + ln) * 32 + g * 8);
        f32x4 s[4];
        #pragma unroll
        for (int qt = 0; qt < 4; ++qt)
            s[qt] = MFMA_B16(kf, qf[qt], vzero);

        // per-query max over this wave's 16 keys (in-lane over r, then 4 lane-groups)
        float pm[4];
        #pragma unroll
        for (int qt = 0; qt < 4; ++qt) {
            float m = fmaxf(fmaxf(s[qt][0], s[qt][1]), fmaxf(s[qt][2], s[qt][3]));
            m = fmaxf(m, __shfl_xor(m, 16));
            m = fmaxf(m, __shfl_xor(m, 32));
            pm[qt] = m;
        }
        if (g == 0) {
            #pragma unroll
            for (int qt = 0; qt < 4; ++qt) smax[(qt * 16 + ln) * 4 + w] = pm[qt];
        }
        __syncthreads();   // B1

        float m_new[4], scale[4], ps[4];
        #pragma unroll
        for (int qt = 0; qt < 4; ++qt) {
            f32x4 t = *(const f32x4*)(smax + (qt * 16 + ln) * 4);
            float tm = fmaxf(fmaxf(t[0], t[1]), fmaxf(t[2], t[3]));
            m_new[qt] = fmaxf(m_run[qt], tm);
            scale[qt] = __expf(m_run[qt] - m_new[qt]);
        }
        // P = exp(S - m_new): partial sums + bf16 pack -> P_lds[q][m]
        #pragma unroll
        for (int qt = 0; qt < 4; ++qt) {
            float p0 = __expf(s[qt][0] - m_new[qt]);
            float p1 = __expf(s[qt][1] - m_new[qt]);
            float p2 = __expf(s[qt][2] - m_new[qt]);
            float p3 = __expf(s[qt][3] - m_new[qt]);
            float sum = (p0 + p1) + (p2 + p3);
            sum += __shfl_xor(sum, 16);
            sum += __shfl_xor(sum, 32);
            ps[qt] = sum;
            uint2 pk;
            pk.x = (unsigned int)f2b(p0) | ((unsigned int)f2b(p1) << 16);
            pk.y = (unsigned int)f2b(p2) | ((unsigned int)f2b(p3) << 16);
            *(uint2*)(P_lds + (qt * 16 + ln) * PSTR + w * 16 + g * 4) = pk;
        }
        if (g == 0) {
            #pragma unroll
            for (int qt = 0; qt < 4; ++qt) ssum[(qt * 16 + ln) * 4 + w] = ps[qt];
        }
        __syncthreads();   // B2

        #pragma unroll
        for (int qt = 0; qt < 4; ++qt) {
            f32x4 t = *(const f32x4*)(ssum + (qt * 16 + ln) * 4);
            l_run[qt] = l_run[qt] * scale[qt] + ((t[0] + t[1]) + (t[2] + t[3]));
            m_run[qt] = m_new[qt];
            #pragma unroll
            for (int ct = 0; ct < 4; ++ct) {
                acc[qt][ct][0] *= scale[qt];
                acc[qt][ct][1] *= scale[qt];
                acc[qt][ct][2] *= scale[qt];
                acc[qt][ct][3] *= scale[qt];
            }
        }

        // PV: A = v[c][m] (16B contiguous, 64B-cacheline perfect), B = P^T from LDS
        #pragma unroll
        for (int kk = 0; kk < 2; ++kk) {
            bf16x8 pf[4];
            #pragma unroll
            for (int qt = 0; qt < 4; ++qt)
                pf[qt] = *(const bf16x8*)(P_lds + (qt * 16 + ln) * PSTR + kk * 32 + g * 8);
            #pragma unroll
            for (int ct = 0; ct < 4; ++ct) {
                const bf16x8 vf = *(const bf16x8*)(
                    vv + ((size_t)b * CIN + w * 64 + ct * 16 + ln) * NPIX + k0 + kk * 32 + g * 8);
                #pragma unroll
                for (int qt = 0; qt < 4; ++qt)
                    acc[qt][ct] = MFMA_B16(vf, pf[qt], acc[qt][ct]);
            }
        }
    }

    // epilogue: y = acc/l, out = x + gamma*y
    #pragma unroll
    for (int qt = 0; qt < 4; ++qt) {
        const float inv = 1.0f / l_run[qt];
        const int n = qbase + qt * 16 + ln;
        #pragma unroll
        for (int ct = 0; ct < 4; ++ct) {
            #pragma unroll
            for (int r = 0; r < 4; ++r) {
                const int c = w * 64 + ct * 16 + g * 4 + r;
                const size_t idx = ((size_t)b * CIN + c) * NPIX + n;
                out[idx] = x[idx] + gamma * (acc[qt][ct][r] * inv);
            }
        }
    }
}

extern "C" void kernel_launch(void* const* d_in, const int* in_sizes, int n_in,
                              void* d_out, int out_size, void* d_ws, size_t ws_size,
                              hipStream_t stream) {
    const float* x     = (const float*)d_in[0];
    const float* Wq    = (const float*)d_in[1];
    const float* bq    = (const float*)d_in[2];
    const float* Wk    = (const float*)d_in[3];
    const float* bk    = (const float*)d_in[4];
    const float* Wv    = (const float*)d_in[5];
    const float* bv    = (const float*)d_in[6];
    const float* gamma = (const float*)d_in[7];

    // workspace layout (bf16): qT 2MB | kT 2MB | v 16MB   (total 20MB)
    unsigned short* qT = (unsigned short*)d_ws;
    unsigned short* kT = qT + (size_t)NBATCH * NPIX * 32;
    unsigned short* vv = kT + (size_t)NBATCH * NPIX * 32;

    qkv_kernel<<<512, 256, 0, stream>>>(x, Wq, bq, Wk, bk, Wv, bv, qT, kT, vv);
    attn_kernel<<<512, 256, 0, stream>>>(x, gamma, qT, kT, vv, (float*)d_out);
}